// Round 2
// baseline (1394.423 us; speedup 1.0000x reference)
//
#include <hip/hip_runtime.h>

// LSTM_26912265077001: 2-layer LSTM (H=51, IN=1), T=512, B=1024, fp32.
//
// V3: kill the LDS broadcast bottleneck.
// V2 was LDS-return-BW bound: 624 ds_read_b128/CU/iter (every lane re-read
// the full 4-batch h vector) ~= 5000 cy/iter on the one-per-CU LDS pipe.
// V3 broadcasts h through SGPRs instead: each wave loads h[b][lane] into
// VGPRs once (2 ds_read_b32), then v_readlane -> SGPR per k, reused by
// 4 FMAs (2 rows x 2 batches per thread). LDS now carries only the small
// handoffs (h write-back, gate buffers, x).
//
// Thread layout (768 = 12 waves, roles wave-aligned, batch-group per-wave
// uniform so readlane broadcast is correct):
//   waves 0-3 : R1 = W_hh1 matvec (+E1 update, owns c1)
//   waves 4-7 : R2 = W_ih2 matvec (+E2 update, owns c2)
//   waves 8-11: R3 = W_hh2 matvec; wave 11 lanes 40-43 = output dot
//   within a role: wave pair (lw&1) spans 102 row-pairs; g=lw>>1 picks
//   batches {0,1} or {2,3}. Thread owns rows {rp, rp+102}.
//
// Pipeline (2 barriers/iter), same dependency structure as V2:
//   phase 1: R1: gates1(it) | R2: g2a(it-1)=b2+W_ih2*h1[it-1]
//            R3: g2b(it-1)=W_hh2*h2[it-2] | OUT: out[it-2]
//   phase 2: E1: h1[it],c1  | E2: h2[it-1],c2

#define Hs   51
#define HP   52
#define G4   204
#define Ts   512
#define Bs   1024
#define NB   4
#define NT   768

__device__ __forceinline__ float sig_(float x) {
    return 1.0f / (1.0f + __expf(-x));
}
__device__ __forceinline__ float tanh_(float x) {
    float e = __expf(2.0f * x);
    return 1.0f - 2.0f / (e + 1.0f);
}
// wave-uniform broadcast of lane k's value via SGPR (VALU pipe, not LDS)
__device__ __forceinline__ float bcast_(float v, int k) {
    return __int_as_float(__builtin_amdgcn_readlane(__float_as_int(v), k));
}

__global__ __launch_bounds__(NT, 3) void lstm2_kernel(
    const float* __restrict__ x,      // (T, B, 1)
    const float* __restrict__ W_ih1,  // (204, 1)
    const float* __restrict__ W_hh1,  // (204, 51)
    const float* __restrict__ b_ih1,  // (204,)
    const float* __restrict__ b_hh1,  // (204,)
    const float* __restrict__ W_ih2,  // (204, 51)
    const float* __restrict__ W_hh2,  // (204, 51)
    const float* __restrict__ b_ih2,  // (204,)
    const float* __restrict__ b_hh2,  // (204,)
    const float* __restrict__ W_lin,  // (1, 51)
    const float* __restrict__ b_lin,  // (1,)
    float* __restrict__ out)          // (B, T)
{
    __shared__ __align__(16) float xs[Ts][NB];
    __shared__ __align__(16) float h1b_[2][NB][HP];
    __shared__ __align__(16) float h2b_[2][NB][HP];
    __shared__ __align__(16) float g1 [NB][G4];
    __shared__ __align__(16) float g2a[NB][G4];
    __shared__ __align__(16) float g2b[NB][G4];
    __shared__ __align__(16) float wlin_s[HP];
    __shared__ float blin_s;

    const int tid  = threadIdx.x;
    const int lane = tid & 63;
    const int wv   = tid >> 6;        // 0..11
    const int role = wv >> 2;         // 0,1,2
    const int lw   = wv & 3;          // wave within role
    const int g    = lw >> 1;         // batch-group, per-wave uniform
    const int rp   = ((lw & 1) << 6) + lane;   // 0..127, valid < 102
    const bool mv  = rp < 102;
    const int b0   = 2 * g, b1 = b0 + 1;
    const int bg0  = blockIdx.x * NB;

    // ---- one-time preload ----
    for (int idx = tid; idx < Ts * NB; idx += NT) {
        int tt = idx >> 2, b = idx & 3;
        xs[tt][b] = x[tt * Bs + bg0 + b];
    }
    if (tid < 2 * NB * HP) {
        ((float*)h1b_)[tid] = 0.f;
        ((float*)h2b_)[tid] = 0.f;
    }
    if (tid < HP) wlin_s[tid] = (tid < Hs) ? W_lin[tid] : 0.f;
    if (tid == 0) blin_s = b_lin[0];

    // ---- weights: 2 rows {rp, rp+102} of this role's matrix ----
    float wA[Hs], wB[Hs];
    float bsA = 0.f, bsB = 0.f, wihA = 0.f, wihB = 0.f;
    if (mv) {
        const int r0 = rp, r1 = rp + 102;
        const float* M = (role == 0) ? W_hh1 : (role == 1) ? W_ih2 : W_hh2;
        #pragma unroll
        for (int k = 0; k < Hs; ++k) {
            wA[k] = M[r0 * Hs + k];
            wB[k] = M[r1 * Hs + k];
        }
        if (role == 0) {
            bsA = b_ih1[r0] + b_hh1[r0];
            bsB = b_ih1[r1] + b_hh1[r1];
            wihA = W_ih1[r0];
            wihB = W_ih1[r1];
        } else if (role == 1) {
            bsA = b_ih2[r0] + b_hh2[r0];
            bsB = b_ih2[r1] + b_hh2[r1];
        }
    }

    // E-update mapping (E1 on role-0 mv threads, E2 on role-1 mv threads)
    int eb = 0, ej = 0;
    if (mv && role < 2) {
        int c = g * 102 + rp;         // 0..203
        eb = c / 51;
        ej = c - eb * 51;
    }
    const bool isOut = (wv == 11) && (lane >= 40) && (lane < 44);
    const int  ob    = lane - 40;

    float cc = 0.f;                   // c1 (role 0) / c2 (role 1)
    __syncthreads();

    for (int it = 0; it <= Ts; ++it) {
        const int pr1 = (it - 1) & 1; // h1[it-1] parity
        const int pr2 = it & 1;       // h2[it-2] parity

        // ---- phase 1: h into wave registers (lane j holds h[b][j]) ----
        float h1A = 0.f, h1B = 0.f, h2A = 0.f, h2B = 0.f;
        if (lane < HP) {
            h1A = h1b_[pr1][b0][lane];
            h1B = h1b_[pr1][b1][lane];
            h2A = h2b_[pr2][b0][lane];
            h2B = h2b_[pr2][b1][lane];
        }

        if (role == 0) {
            if (mv && it < Ts) {
                float xv0 = xs[it][b0], xv1 = xs[it][b1];
                float aA0 = fmaf(wihA, xv0, bsA);
                float aB0 = fmaf(wihB, xv0, bsB);
                float aA1 = fmaf(wihA, xv1, bsA);
                float aB1 = fmaf(wihB, xv1, bsB);
                #pragma unroll
                for (int k = 0; k < Hs; ++k) {
                    float ha = bcast_(h1A, k);
                    float hb = bcast_(h1B, k);
                    aA0 = fmaf(wA[k], ha, aA0);
                    aB0 = fmaf(wB[k], ha, aB0);
                    aA1 = fmaf(wA[k], hb, aA1);
                    aB1 = fmaf(wB[k], hb, aB1);
                }
                g1[b0][rp]       = aA0;
                g1[b0][rp + 102] = aB0;
                g1[b1][rp]       = aA1;
                g1[b1][rp + 102] = aB1;
            }
        } else if (role == 1) {
            if (mv && it >= 1) {
                float aA0 = bsA, aB0 = bsB, aA1 = bsA, aB1 = bsB;
                #pragma unroll
                for (int k = 0; k < Hs; ++k) {
                    float ha = bcast_(h1A, k);
                    float hb = bcast_(h1B, k);
                    aA0 = fmaf(wA[k], ha, aA0);
                    aB0 = fmaf(wB[k], ha, aB0);
                    aA1 = fmaf(wA[k], hb, aA1);
                    aB1 = fmaf(wB[k], hb, aB1);
                }
                g2a[b0][rp]       = aA0;
                g2a[b0][rp + 102] = aB0;
                g2a[b1][rp]       = aA1;
                g2a[b1][rp + 102] = aB1;
            }
        } else {
            if (mv && it >= 1) {
                float aA0 = 0.f, aB0 = 0.f, aA1 = 0.f, aB1 = 0.f;
                #pragma unroll
                for (int k = 0; k < Hs; ++k) {
                    float ha = bcast_(h2A, k);
                    float hb = bcast_(h2B, k);
                    aA0 = fmaf(wA[k], ha, aA0);
                    aB0 = fmaf(wB[k], ha, aB0);
                    aA1 = fmaf(wA[k], hb, aA1);
                    aB1 = fmaf(wB[k], hb, aB1);
                }
                g2b[b0][rp]       = aA0;
                g2b[b0][rp + 102] = aB0;
                g2b[b1][rp]       = aA1;
                g2b[b1][rp + 102] = aB1;
            }
            if (isOut && it >= 2) {    // out[it-2] = W_lin . h2[it-2] + b
                const float4* hb4 = (const float4*)h2b_[pr2][ob];
                const float4* wv4 = (const float4*)wlin_s;
                float s = blin_s;
                #pragma unroll
                for (int k = 0; k < HP / 4; ++k) {
                    float4 a = hb4[k], w = wv4[k];
                    s += a.x * w.x + a.y * w.y + a.z * w.z + a.w * w.w;
                }
                out[(bg0 + ob) * Ts + (it - 2)] = s;
            }
        }
        __syncthreads();

        // ---- phase 2: elementwise updates ----
        if (mv && role == 0) {
            if (it < Ts) {
                float iv = sig_ (g1[eb][ej]);
                float fv = sig_ (g1[eb][ej + Hs]);
                float gv = tanh_(g1[eb][ej + 2 * Hs]);
                float ov = sig_ (g1[eb][ej + 3 * Hs]);
                cc = fmaf(fv, cc, iv * gv);
                h1b_[it & 1][eb][ej] = ov * tanh_(cc);
            }
        } else if (mv && role == 1) {
            if (it >= 1) {
                float s0 = g2a[eb][ej]          + g2b[eb][ej];
                float s1 = g2a[eb][ej + Hs]     + g2b[eb][ej + Hs];
                float s2 = g2a[eb][ej + 2 * Hs] + g2b[eb][ej + 2 * Hs];
                float s3 = g2a[eb][ej + 3 * Hs] + g2b[eb][ej + 3 * Hs];
                float iv = sig_(s0);
                float fv = sig_(s1);
                float gv = tanh_(s2);
                float ov = sig_(s3);
                cc = fmaf(fv, cc, iv * gv);
                h2b_[(it - 1) & 1][eb][ej] = ov * tanh_(cc);
            }
        }
        __syncthreads();
    }

    // ---- final output t = T-1 (h2[T-1] is in parity (Ts-1)&1) ----
    if (isOut) {
        const float4* hb4 = (const float4*)h2b_[(Ts - 1) & 1][ob];
        const float4* wv4 = (const float4*)wlin_s;
        float s = blin_s;
        #pragma unroll
        for (int k = 0; k < HP / 4; ++k) {
            float4 a = hb4[k], w = wv4[k];
            s += a.x * w.x + a.y * w.y + a.z * w.z + a.w * w.w;
        }
        out[(bg0 + ob) * Ts + (Ts - 1)] = s;
    }
}

extern "C" void kernel_launch(void* const* d_in, const int* in_sizes, int n_in,
                              void* d_out, int out_size, void* d_ws, size_t ws_size,
                              hipStream_t stream) {
    const float* x     = (const float*)d_in[0];
    const float* W_ih1 = (const float*)d_in[1];
    const float* W_hh1 = (const float*)d_in[2];
    const float* b_ih1 = (const float*)d_in[3];
    const float* b_hh1 = (const float*)d_in[4];
    const float* W_ih2 = (const float*)d_in[5];
    const float* W_hh2 = (const float*)d_in[6];
    const float* b_ih2 = (const float*)d_in[7];
    const float* b_hh2 = (const float*)d_in[8];
    const float* W_lin = (const float*)d_in[9];
    const float* b_lin = (const float*)d_in[10];
    float* out = (float*)d_out;

    lstm2_kernel<<<Bs / NB, NT, 0, stream>>>(
        x, W_ih1, W_hh1, b_ih1, b_hh1,
        W_ih2, W_hh2, b_ih2, b_hh2, W_lin, b_lin, out);
}

// Round 3
// 1028.406 us; speedup vs baseline: 1.3559x; 1.3559x over previous
//
#include <hip/hip_runtime.h>

// LSTM_26912265077001: 2-layer LSTM (H=51, IN=1), T=512, B=1024, fp32.
//
// V4: MFMA split-bf16 (hi+lo) emulation of the fp32 matvecs.
//  - gates1(4x204) = [h1(51), x(1)] (K=64) x B1(204x64)^T   -> 2 ksteps
//  - gates2(4x204) = [h1(51), h2(51)] (K=128) x B2(204x128)^T -> 4 ksteps
//    (W_ih2 and W_hh2 fused into ONE accumulator pass)
//  - Each fp32 value v = hi + lo (two bf16); products use all 4 cross
//    terms -> ~fp32-accurate (input quant ~2^-17 rel).
//  - Weights (B-fragments) preloaded ONCE into registers: wave w owns
//    N-tiles {w, w+4, w+8} (+tile 12 for wave 0). 1 wave/SIMD, VGPR~300.
//  - h state stored in LDS as bf16 hi/lo arrays shaped for direct
//    ds_read_b128 A-fragment loads (row stride padded: 72/136 ushorts).
//  - Same 2-barrier pipeline as V3: L2 computes step it-1 while L1
//    computes step it; out[it-2] read from fp32 h2f (no bf16 loss on y).
//
// MFMA 16x16x32 bf16 layout (guide §3, m89-verified D-map):
//   A: row = lane&15 (batch; rows 4-15 zero), k = (lane>>4)*8 + j
//   B: col = lane&15 (gate row),              k = (lane>>4)*8 + j
//   D: col = lane&15, row(batch) = (lane>>4)*4 + reg -> lanes 0-15 hold
//      all 4 batches in regs 0-3.  (A/B share the k-map, so any k-perm
//      error cancels between them.)

#define Hs   51
#define G4   204
#define Ts   512
#define Bs   1024
#define NB   4
#define NT   256
#define S1   72      // a1 row stride in ushorts (144B, 16B-aligned, un-aliased)
#define S2   136     // a2 row stride in ushorts (272B)

typedef __attribute__((ext_vector_type(8))) short  bf16x8;  // 8 bf16 = 4 VGPR
typedef __attribute__((ext_vector_type(4))) float  f32x4;

__device__ __forceinline__ float sig_(float x)  { return 1.0f / (1.0f + __expf(-x)); }
__device__ __forceinline__ float tanh_(float x) { float e = __expf(2.0f * x); return 1.0f - 2.0f / (e + 1.0f); }
__device__ __forceinline__ unsigned short bfh_(float x) {   // fp32 -> bf16 (RNE)
    unsigned u = __float_as_uint(x);
    return (unsigned short)((u + 0x7FFFu + ((u >> 16) & 1u)) >> 16);
}
__device__ __forceinline__ float bff_(unsigned short h) {   // bf16 -> fp32
    return __uint_as_float(((unsigned)h) << 16);
}

__global__ __launch_bounds__(NT, 1) void lstm2_kernel(
    const float* __restrict__ x,      // (T, B, 1)
    const float* __restrict__ W_ih1,  // (204, 1)
    const float* __restrict__ W_hh1,  // (204, 51)
    const float* __restrict__ b_ih1,  // (204,)
    const float* __restrict__ b_hh1,  // (204,)
    const float* __restrict__ W_ih2,  // (204, 51)
    const float* __restrict__ W_hh2,  // (204, 51)
    const float* __restrict__ b_ih2,  // (204,)
    const float* __restrict__ b_hh2,  // (204,)
    const float* __restrict__ W_lin,  // (1, 51)
    const float* __restrict__ b_lin,  // (1,)
    float* __restrict__ out)          // (B, T)
{
    __shared__ __align__(16) float  xs[Ts][NB];            // 8 KB
    __shared__ __align__(16) unsigned short a1h[16 * S1];  // [h1(51), x(1), 0..] hi
    __shared__ __align__(16) unsigned short a1l[16 * S1];  // lo
    __shared__ __align__(16) unsigned short a2h[16 * S2];  // [h1(51), h2(51), 0..] hi
    __shared__ __align__(16) unsigned short a2l[16 * S2];  // lo
    __shared__ __align__(16) float  g1s[NB][208];          // layer-1 gates
    __shared__ __align__(16) float  g2s[NB][208];          // layer-2 gates
    __shared__ __align__(16) float  h2f[NB][52];           // h2 fp32 (for y)
    __shared__ __align__(16) float  wlin_s[52];
    __shared__ float blin_s;

    const int tid  = threadIdx.x;
    const int lane = tid & 63;
    const int wv   = tid >> 6;        // 0..3
    const int m    = lane & 15;       // A-row / D-col index
    const int ch   = lane >> 4;       // k-chunk
    const int nT   = (wv == 0) ? 4 : 3;
    const int bg0  = blockIdx.x * NB;

    // ---- one-time init: LDS ----
    for (int i = tid; i < Ts * NB; i += NT) {
        int tt = i >> 2, b = i & 3;
        xs[tt][b] = x[tt * Bs + bg0 + b];
    }
    for (int i = tid; i < 16 * S1; i += NT) { a1h[i] = 0; a1l[i] = 0; }
    for (int i = tid; i < 16 * S2; i += NT) { a2h[i] = 0; a2l[i] = 0; }
    for (int i = tid; i < NB * 52; i += NT) ((float*)h2f)[i] = 0.f;
    if (tid < 52) wlin_s[tid] = (tid < Hs) ? W_lin[tid] : 0.f;
    if (tid == 0) blin_s = b_lin[0];
    if (tid >= 208 && tid < 212) {    // x[0] into a1 slot 51
        int b = tid - 208;
        float xv = x[0 * Bs + bg0 + b];
        unsigned short hh = bfh_(xv);
        a1h[b * S1 + Hs] = hh;
        a1l[b * S1 + Hs] = bfh_(xv - bff_(hh));
    }

    // ---- one-time init: B-fragments (weights) into registers ----
    bf16x8 B1h[4][2], B1l[4][2];      // [tile][kstep]
    bf16x8 B2h[4][4], B2l[4][4];
    float  bias1f[4], bias2f[4];
    #pragma unroll
    for (int i = 0; i < 4; ++i) {
        if (i >= nT) continue;
        const int t = (i < 3) ? (wv + 4 * i) : 12;
        const int r = t * 16 + m;
        bias1f[i] = (r < G4) ? (b_ih1[r] + b_hh1[r]) : 0.f;
        bias2f[i] = (r < G4) ? (b_ih2[r] + b_hh2[r]) : 0.f;
        #pragma unroll
        for (int s = 0; s < 2; ++s) {
            bf16x8 h8, l8;
            #pragma unroll
            for (int j = 0; j < 8; ++j) {
                const int k = s * 32 + ch * 8 + j;
                float v = 0.f;
                if (r < G4) {
                    if (k < Hs)       v = W_hh1[r * Hs + k];
                    else if (k == Hs) v = W_ih1[r];
                }
                unsigned short hh = bfh_(v);
                h8[j] = (short)hh;
                l8[j] = (short)bfh_(v - bff_(hh));
            }
            B1h[i][s] = h8; B1l[i][s] = l8;
        }
        #pragma unroll
        for (int s = 0; s < 4; ++s) {
            bf16x8 h8, l8;
            #pragma unroll
            for (int j = 0; j < 8; ++j) {
                const int k = s * 32 + ch * 8 + j;
                float v = 0.f;
                if (r < G4) {
                    if (k < Hs)          v = W_ih2[r * Hs + k];
                    else if (k < 2 * Hs) v = W_hh2[r * Hs + (k - Hs)];
                }
                unsigned short hh = bfh_(v);
                h8[j] = (short)hh;
                l8[j] = (short)bfh_(v - bff_(hh));
            }
            B2h[i][s] = h8; B2l[i][s] = l8;
        }
    }

    float c1 = 0.f, c2 = 0.f;         // cell states (threads 0..203)
    __syncthreads();

    for (int it = 0; it <= Ts; ++it) {
        // ================= phase M: MFMAs + output dot =================
        bf16x8 A1h_[2], A1l_[2], A2h_[4], A2l_[4];
        if (it < Ts) {
            #pragma unroll
            for (int s = 0; s < 2; ++s) {
                A1h_[s] = *(const bf16x8*)&a1h[m * S1 + s * 32 + ch * 8];
                A1l_[s] = *(const bf16x8*)&a1l[m * S1 + s * 32 + ch * 8];
            }
        }
        if (it >= 1) {
            #pragma unroll
            for (int s = 0; s < 4; ++s) {
                A2h_[s] = *(const bf16x8*)&a2h[m * S2 + s * 32 + ch * 8];
                A2l_[s] = *(const bf16x8*)&a2l[m * S2 + s * 32 + ch * 8];
            }
        }

        f32x4 acc1[4], acc2[4];
        #pragma unroll
        for (int i = 0; i < 4; ++i) {
            if (i >= nT) continue;
            if (it < Ts) {
                f32x4 a = {bias1f[i], bias1f[i], bias1f[i], bias1f[i]};
                #pragma unroll
                for (int s = 0; s < 2; ++s) {
                    a = __builtin_amdgcn_mfma_f32_16x16x32_bf16(A1h_[s], B1h[i][s], a, 0, 0, 0);
                    a = __builtin_amdgcn_mfma_f32_16x16x32_bf16(A1l_[s], B1h[i][s], a, 0, 0, 0);
                    a = __builtin_amdgcn_mfma_f32_16x16x32_bf16(A1h_[s], B1l[i][s], a, 0, 0, 0);
                    a = __builtin_amdgcn_mfma_f32_16x16x32_bf16(A1l_[s], B1l[i][s], a, 0, 0, 0);
                }
                acc1[i] = a;
            }
            if (it >= 1) {
                f32x4 a = {bias2f[i], bias2f[i], bias2f[i], bias2f[i]};
                #pragma unroll
                for (int s = 0; s < 4; ++s) {
                    a = __builtin_amdgcn_mfma_f32_16x16x32_bf16(A2h_[s], B2h[i][s], a, 0, 0, 0);
                    a = __builtin_amdgcn_mfma_f32_16x16x32_bf16(A2l_[s], B2h[i][s], a, 0, 0, 0);
                    a = __builtin_amdgcn_mfma_f32_16x16x32_bf16(A2h_[s], B2l[i][s], a, 0, 0, 0);
                    a = __builtin_amdgcn_mfma_f32_16x16x32_bf16(A2l_[s], B2l[i][s], a, 0, 0, 0);
                }
                acc2[i] = a;
            }
        }
        if (lane < 16) {              // lanes 0-15 hold batches 0-3 in regs 0-3
            #pragma unroll
            for (int i = 0; i < 4; ++i) {
                if (i >= nT) continue;
                const int t   = (i < 3) ? (wv + 4 * i) : 12;
                const int col = t * 16 + m;
                if (it < Ts) {
                    g1s[0][col] = acc1[i].x; g1s[1][col] = acc1[i].y;
                    g1s[2][col] = acc1[i].z; g1s[3][col] = acc1[i].w;
                }
                if (it >= 1) {
                    g2s[0][col] = acc2[i].x; g2s[1][col] = acc2[i].y;
                    g2s[2][col] = acc2[i].z; g2s[3][col] = acc2[i].w;
                }
            }
        }
        if (it >= 2 && tid >= 64 && tid < 68) {   // y[it-2] from fp32 h2
            const int b = tid - 64;
            const float4* hb = (const float4*)&h2f[b][0];
            const float4* wv4 = (const float4*)&wlin_s[0];
            float s = blin_s;
            #pragma unroll
            for (int k = 0; k < 13; ++k) {
                float4 a = hb[k], w = wv4[k];
                s += a.x * w.x + a.y * w.y + a.z * w.z + a.w * w.w;
            }
            out[(bg0 + b) * Ts + (it - 2)] = s;
        }
        __syncthreads();

        // ================= phase E: elementwise updates =================
        if (tid < G4) {
            const int b = tid / Hs, j = tid - b * Hs;
            if (it < Ts) {            // layer 1 -> h1[it]
                float gi = g1s[b][j],           gf = g1s[b][j + Hs];
                float gg = g1s[b][j + 2 * Hs],  go = g1s[b][j + 3 * Hs];
                c1 = fmaf(sig_(gf), c1, sig_(gi) * tanh_(gg));
                float h1 = sig_(go) * tanh_(c1);
                unsigned short hh = bfh_(h1);
                unsigned short hl = bfh_(h1 - bff_(hh));
                a1h[b * S1 + j] = hh; a1l[b * S1 + j] = hl;
                a2h[b * S2 + j] = hh; a2l[b * S2 + j] = hl;
            }
            if (it >= 1) {            // layer 2 -> h2[it-1]
                float gi = g2s[b][j],           gf = g2s[b][j + Hs];
                float gg = g2s[b][j + 2 * Hs],  go = g2s[b][j + 3 * Hs];
                c2 = fmaf(sig_(gf), c2, sig_(gi) * tanh_(gg));
                float h2 = sig_(go) * tanh_(c2);
                unsigned short hh = bfh_(h2);
                unsigned short hl = bfh_(h2 - bff_(hh));
                a2h[b * S2 + Hs + j] = hh; a2l[b * S2 + Hs + j] = hl;
                h2f[b][j] = h2;
            }
        } else if (tid >= 208 && tid < 212 && it + 1 < Ts) {
            const int b = tid - 208;  // stage x[it+1] into a1 slot 51
            float xv = xs[it + 1][b];
            unsigned short hh = bfh_(xv);
            a1h[b * S1 + Hs] = hh;
            a1l[b * S1 + Hs] = bfh_(xv - bff_(hh));
        }
        __syncthreads();
    }

    // ---- final output y[T-1] (h2f holds h2[T-1] after it=Ts) ----
    if (tid >= 64 && tid < 68) {
        const int b = tid - 64;
        const float4* hb = (const float4*)&h2f[b][0];
        const float4* wv4 = (const float4*)&wlin_s[0];
        float s = blin_s;
        #pragma unroll
        for (int k = 0; k < 13; ++k) {
            float4 a = hb[k], w = wv4[k];
            s += a.x * w.x + a.y * w.y + a.z * w.z + a.w * w.w;
        }
        out[(bg0 + b) * Ts + (Ts - 1)] = s;
    }
}

extern "C" void kernel_launch(void* const* d_in, const int* in_sizes, int n_in,
                              void* d_out, int out_size, void* d_ws, size_t ws_size,
                              hipStream_t stream) {
    const float* x     = (const float*)d_in[0];
    const float* W_ih1 = (const float*)d_in[1];
    const float* W_hh1 = (const float*)d_in[2];
    const float* b_ih1 = (const float*)d_in[3];
    const float* b_hh1 = (const float*)d_in[4];
    const float* W_ih2 = (const float*)d_in[5];
    const float* W_hh2 = (const float*)d_in[6];
    const float* b_ih2 = (const float*)d_in[7];
    const float* b_hh2 = (const float*)d_in[8];
    const float* W_lin = (const float*)d_in[9];
    const float* b_lin = (const float*)d_in[10];
    float* out = (float*)d_out;

    lstm2_kernel<<<Bs / NB, NT, 0, stream>>>(
        x, W_ih1, W_hh1, b_ih1, b_hh1,
        W_ih2, W_hh2, b_ih2, b_hh2, W_lin, b_lin, out);
}